// Round 4
// baseline (170.184 us; speedup 1.0000x reference)
//
#include <hip/hip_runtime.h>
#include <hip/hip_bf16.h>

typedef __attribute__((ext_vector_type(4))) float  f32x4;
typedef __attribute__((ext_vector_type(8))) short  bf16x8;
typedef __attribute__((ext_vector_type(4))) short  bf16x4v;

#define BM 128
#define BN 128
#define BK 32
#define PADK 40   // only used by the f32-fallback staging path
#define EPAD 68   // f32 elems per epilogue LDS row (64 + 4 pad)

__device__ __forceinline__ unsigned short f2bf(float f) {
  __hip_bfloat16 h = __float2bfloat16(f);
  unsigned short u; __builtin_memcpy(&u, &h, 2); return u;
}

// Fully-inline sincos: f64 Cody-Waite reduction (|x| small: x ~ N(0,1)),
// musl-style f32 kernels. No library call -> no call-ABI spills, no scratch.
__device__ __forceinline__ void my_sincos(float xf, float& s_out, float& c_out) {
  const double xd = (double)xf;
  const double kd = __builtin_rint(xd * 0.636619772367581343076);   // x * 2/pi
  const int    q  = (int)kd;
  double rd = __builtin_fma(-kd, 1.5707963267948966,    xd);        // pio2_hi (f64)
  rd        = __builtin_fma(-kd, 6.123233995736766e-17, rd);        // pio2_lo
  const float r = (float)rd;
  const float z = r * r;
  const float ps = fmaf(z, fmaf(z, fmaf(z, 2.7183114939898219e-06f,
                                           -1.9839334836096632e-04f),
                                   8.3333293858894632e-03f),
                        -1.6666666641626524e-01f);
  const float sr = fmaf(r * z, ps, r);                              // sin(r)
  const float pc = fmaf(z, fmaf(z, fmaf(z, 2.4390448796277409e-05f,
                                           -1.3886763774609929e-03f),
                                   4.1666623323739063e-02f),
                        -4.9999999725103100e-01f);
  const float cr = fmaf(z, pc, 1.0f);                               // cos(r)
  const bool swap = (q & 1) != 0;
  float s1 = swap ? cr : sr;
  float c1 = swap ? sr : cr;
  if (q & 2)       s1 = -s1;
  if ((q + 1) & 2) c1 = -c1;
  s_out = s1; c_out = c1;
}

// ---- kernel 1: W (H,H) f32 row-major -> Wt (H,H) bf16, transposed ----
__global__ __launch_bounds__(256)
void transpose_W(const float* __restrict__ W, unsigned short* __restrict__ Wt, int H) {
  __shared__ float tile[64][65];
  const int k0 = blockIdx.y * 64;
  const int n0 = blockIdx.x * 64;
  const int t = threadIdx.x;
  #pragma unroll
  for (int it = 0; it < 4; ++it) {
    int q = it * 256 + t;
    int r = q >> 4, c4 = (q & 15) << 2;
    f32x4 v = *(const f32x4*)&W[(size_t)(k0 + r) * H + n0 + c4];
    tile[r][c4 + 0] = v[0]; tile[r][c4 + 1] = v[1];
    tile[r][c4 + 2] = v[2]; tile[r][c4 + 3] = v[3];
  }
  __syncthreads();
  #pragma unroll
  for (int it = 0; it < 4; ++it) {
    int q = it * 256 + t;
    int r = q >> 4, c4 = (q & 15) << 2;
    bf16x4v o;
    #pragma unroll
    for (int j = 0; j < 4; ++j) o[j] = (short)f2bf(tile[c4 + j][r]);
    *(bf16x4v*)&Wt[(size_t)(n0 + r) * H + k0 + c4] = o;
  }
}

// ---- kernel 1b: x f32 -> bf16 ----
__global__ __launch_bounds__(256)
void cvt_x(const float* __restrict__ x, unsigned short* __restrict__ xb, int n4) {
  int i = blockIdx.x * 256 + threadIdx.x;
  const int stride = gridDim.x * 256;
  for (; i < n4; i += stride) {
    f32x4 v = ((const f32x4*)x)[i];
    bf16x4v o;
    #pragma unroll
    for (int j = 0; j < 4; ++j) o[j] = (short)f2bf(v[j]);
    ((bf16x4v*)xb)[i] = o;
  }
}

// ---- kernel 2: fused bf16-MFMA GEMM + inline trig epilogue + ODE scale ----
template <bool XB>
__global__ __launch_bounds__(256, 4)
void gemm_fused(const float* __restrict__ x, const unsigned short* __restrict__ xb,
                const unsigned short* __restrict__ Wt,
                const float* __restrict__ bv, const float* __restrict__ cv,
                const float* __restrict__ dv, float* __restrict__ out,
                float S, int H) {
  // XB path: As/Bs linear [128][32] bf16 (8192 B each, global_load_lds dest).
  // Epilogue Es (17408 B) reuses the same allocation after the K loop.
  __shared__ unsigned char smem[20480];
  unsigned short* As = (unsigned short*)smem;
  unsigned short* Bs = (unsigned short*)(smem + 8192);
  float*          Es = (float*)smem;

  const int tid  = threadIdx.x;
  const int bj   = blockIdx.x;       // N tile (8) -- fast dim
  const int bi   = blockIdx.y;       // M tile (128)
  const int i0   = bi * BM, j0 = bj * BN;
  const int wave = tid >> 6, lane = tid & 63;
  const int wr = wave >> 1, wc = wave & 1;
  const int l16 = lane & 15, lq = lane >> 4;

  f32x4 acc[4][4] = {};

  if constexpr (XB) {
    // per-lane global source element index for the two 1024B issues per wave
    const int q0 = wave * 128 + lane;        // issue 0: tile elem-octet q0
    const int q1 = q0 + 64;                  // issue 1
    const int r0 = q0 >> 2, k80 = (q0 & 3) << 3;
    const int r1 = q1 >> 2, k81 = (q1 & 3) << 3;
    for (int kk = 0; kk < H; kk += BK) {
      __builtin_amdgcn_global_load_lds(
        (const __attribute__((address_space(1))) void*)&xb[(size_t)(i0 + r0) * H + kk + k80],
        (__attribute__((address_space(3))) void*)(smem + wave * 2048), 16, 0, 0);
      __builtin_amdgcn_global_load_lds(
        (const __attribute__((address_space(1))) void*)&xb[(size_t)(i0 + r1) * H + kk + k81],
        (__attribute__((address_space(3))) void*)(smem + wave * 2048 + 1024), 16, 0, 0);
      __builtin_amdgcn_global_load_lds(
        (const __attribute__((address_space(1))) void*)&Wt[(size_t)(j0 + r0) * H + kk + k80],
        (__attribute__((address_space(3))) void*)(smem + 8192 + wave * 2048), 16, 0, 0);
      __builtin_amdgcn_global_load_lds(
        (const __attribute__((address_space(1))) void*)&Wt[(size_t)(j0 + r1) * H + kk + k81],
        (__attribute__((address_space(3))) void*)(smem + 8192 + wave * 2048 + 1024), 16, 0, 0);
      __syncthreads();   // compiler drains vmcnt(0) before s_barrier

      bf16x8 af[4], bfr[4];
      #pragma unroll
      for (int mi = 0; mi < 4; ++mi)
        af[mi] = *(const bf16x8*)&As[(wr * 64 + mi * 16 + l16) * BK + lq * 8];
      #pragma unroll
      for (int ni = 0; ni < 4; ++ni)
        bfr[ni] = *(const bf16x8*)&Bs[(wc * 64 + ni * 16 + l16) * BK + lq * 8];

      #pragma unroll
      for (int mi = 0; mi < 4; ++mi)
        #pragma unroll
        for (int ni = 0; ni < 4; ++ni)
          acc[mi][ni] = __builtin_amdgcn_mfma_f32_16x16x32_bf16(af[mi], bfr[ni], acc[mi][ni], 0, 0, 0);
      __syncthreads();
    }
  } else {
    // fallback: reg-staged f32->bf16 convert path (padded LDS)
    unsigned short* Asp = (unsigned short*)smem;                 // [128][PADK] won't fit 20480;
    unsigned short* Bsp = Asp + BM * PADK;                       // PADK=40 -> 10240+10240=20480 exactly (bytes*2!)
    // NOTE: BM*PADK*2 + BN*PADK*2 = 20480 B total: Asp bytes 0..10239, Bsp bytes 10240..20479.
    for (int kk = 0; kk < H; kk += BK) {
      #pragma unroll
      for (int it = 0; it < 4; ++it) {
        int q = it * 256 + tid;
        int r = q >> 3, k4 = (q & 7) << 2;
        f32x4 v = *(const f32x4*)&x[(size_t)(i0 + r) * H + kk + k4];
        bf16x4v o;
        #pragma unroll
        for (int j = 0; j < 4; ++j) o[j] = (short)f2bf(v[j]);
        *(bf16x4v*)&Asp[r * PADK + k4] = o;
      }
      #pragma unroll
      for (int it = 0; it < 2; ++it) {
        int q = it * 256 + tid;
        int r = q >> 2, k8 = (q & 3) << 3;
        bf16x8 v = *(const bf16x8*)&Wt[(size_t)(j0 + r) * H + kk + k8];
        *(bf16x8*)&Bsp[r * PADK + k8] = v;
      }
      __syncthreads();
      bf16x8 af[4], bfr[4];
      #pragma unroll
      for (int mi = 0; mi < 4; ++mi)
        af[mi] = *(const bf16x8*)&Asp[(wr * 64 + mi * 16 + l16) * PADK + lq * 8];
      #pragma unroll
      for (int ni = 0; ni < 4; ++ni)
        bfr[ni] = *(const bf16x8*)&Bsp[(wc * 64 + ni * 16 + l16) * PADK + lq * 8];
      #pragma unroll
      for (int mi = 0; mi < 4; ++mi)
        #pragma unroll
        for (int ni = 0; ni < 4; ++ni)
          acc[mi][ni] = __builtin_amdgcn_mfma_f32_16x16x32_bf16(af[mi], bfr[ni], acc[mi][ni], 0, 0, 0);
      __syncthreads();
    }
  }

  // ---- epilogue: per-wave LDS transpose, coalesced f32x4 IO, inline trig ----
  // C/D fragment layout: col = l16, row = lq*4 + r  [m89-verified]
  float* ep = Es + wave * (16 * EPAD);
  const int rr = lane >> 2;           // 0..15
  const int cq = (lane & 3) * 16;     // 0,16,32,48
  #pragma unroll
  for (int mi = 0; mi < 4; ++mi) {
    #pragma unroll
    for (int ni = 0; ni < 4; ++ni)
      #pragma unroll
      for (int r = 0; r < 4; ++r)
        ep[(lq * 4 + r) * EPAD + ni * 16 + l16] = acc[mi][ni][r];
    // same-wave ds_write -> ds_read: in-order LDS pipe, compiler waits lgkmcnt.
    const int i  = i0 + wr * 64 + mi * 16 + rr;
    const int jb = j0 + wc * 64 + cq;
    const float* xrow = &x[(size_t)i * H + jb];
    float*       orow = &out[(size_t)i * H + jb];
    #pragma unroll
    for (int t = 0; t < 4; ++t) {
      f32x4 a  = *(const f32x4*)&ep[rr * EPAD + cq + 4 * t];
      f32x4 xv = *(const f32x4*)&xrow[4 * t];
      f32x4 b4 = *(const f32x4*)&bv[jb + 4 * t];
      f32x4 c4 = *(const f32x4*)&cv[jb + 4 * t];
      f32x4 d4 = *(const f32x4*)&dv[jb + 4 * t];
      f32x4 o;
      #pragma unroll
      for (int e = 0; e < 4; ++e) {
        float s, co;
        my_sincos(xv[e], s, co);
        o[e] = S * (a[e] + b4[e] * s + c4[e] * co + d4[e] * (s / co));
      }
      // nontemporal: out is written once, never re-read -> skip RFO
      __builtin_nontemporal_store(o, (f32x4*)&orow[4 * t]);
    }
  }
}

extern "C" void kernel_launch(void* const* d_in, const int* in_sizes, int n_in,
                              void* d_out, int out_size, void* d_ws, size_t ws_size,
                              hipStream_t stream) {
  const float* x = (const float*)d_in[0];
  const float* W = (const float*)d_in[1];
  const float* b = (const float*)d_in[2];
  const float* c = (const float*)d_in[3];
  const float* d = (const float*)d_in[4];
  float* out = (float*)d_out;
  const int H = in_sizes[2];          // 1024
  const int M = in_sizes[0] / H;      // 16384

  // Scalar RK4 factor: y_final = S * z (ODE linear in y, y0 = 0).
  const int NT = 100;
  float ts[NT];
  const float step = (float)(1.0 / 99.0);
  for (int i = 0; i < NT; ++i) ts[i] = (float)i * step;
  ts[NT - 1] = 1.0f;
  double yy = 0.0;
  for (int i = 0; i < NT - 1; ++i) {
    const double t = (double)ts[i], dt = (double)(ts[i + 1] - ts[i]);
    const double k1 = t - yy;
    const double k2 = (t + 0.5 * dt) - (yy + 0.5 * dt * k1);
    const double k3 = (t + 0.5 * dt) - (yy + 0.5 * dt * k2);
    const double k4 = (t + dt) - (yy + dt * k3);
    yy += dt / 6.0 * (k1 + 2.0 * k2 + 2.0 * k3 + k4);
  }
  const float S = (float)yy;

  unsigned short* Wt = (unsigned short*)d_ws;                 // 2 MB bf16 W^T
  dim3 tgrid(H / 64, H / 64);
  transpose_W<<<tgrid, 256, 0, stream>>>(W, Wt, H);

  const size_t need = (size_t)H * H * 2 + (size_t)M * H * 2;  // Wt + x_bf16
  dim3 ggrid(H / BN, M / BM);                                 // x-fast over N tiles

  if (ws_size >= need) {
    unsigned short* xb = Wt + (size_t)H * H;                  // 32 MB bf16 x
    cvt_x<<<2048, 256, 0, stream>>>(x, xb, M * H / 4);
    gemm_fused<true><<<ggrid, 256, 0, stream>>>(x, xb, Wt, b, c, d, out, S, H);
  } else {
    gemm_fused<false><<<ggrid, 256, 0, stream>>>(x, nullptr, Wt, b, c, d, out, S, H);
  }
}